// Round 5
// baseline (319.757 us; speedup 1.0000x reference)
//
#include <hip/hip_runtime.h>

// WassersteinLoss: per-row W1 = (1/N) * sum_i |sort(u)[i] - sort(v)[i]|, mean over rows.
// R5: V=32, 2 waves/row. Negated-partner bitonic: data lives in sign-space
//   z = x ^ (stage_sign ^ pass_bit), so every cross-lane CE is
//   z = min(z, perm(z) ^ 0x80000000) -- no cndmask, no max. Space transitions
//   are 1 xor/elem with precomputed masks. Register tails run ascending-only.
//   Exchange buffer swizzled to exactly 32 KB -> 5 blocks/CU.
// R4 post-mortem: VALU-issue bound (~21K cyc/SIMD static == measured); the
//   3-4 op/elem cross CEs and xor_sign were the fat.

constexpr int N_ELEM  = 4096;
constexpr int V       = 32;     // elements per thread per array
constexpr int THREADS = 256;    // 4 waves = 2 rows per block
constexpr unsigned SGN = 0x80000000u;

// ---- compile-time small stages S=2..16 (directions depend on k only) ----
template<int S>
__device__ __forceinline__ void reg_stage_small(float r[V]) {
    #pragma unroll
    for (int s = S >> 1; s >= 1; s >>= 1) {
        #pragma unroll
        for (int k = 0; k < V; ++k) {
            if ((k & s) == 0) {
                const bool asc = ((k & S) == 0);
                float a = r[k], b = r[k + s];
                float lo = fminf(a, b), hi = fmaxf(a, b);
                r[k]     = asc ? lo : hi;
                r[k + s] = asc ? hi : lo;
            }
        }
    }
}

// ---- ascending-only register merge tail, strides 16..1 (2 ops/CE) ----
__device__ __forceinline__ void reg_tail_asc(float r[V]) {
    #pragma unroll
    for (int s = 16; s >= 1; s >>= 1) {
        #pragma unroll
        for (int k = 0; k < V; ++k) {
            if ((k & s) == 0) {
                float a = r[k], b = r[k + s];
                r[k]     = fminf(a, b);
                r[k + s] = fmaxf(a, b);
            }
        }
    }
}

__device__ __forceinline__ void flip2(float ru[V], float rv[V], unsigned m) {
    #pragma unroll
    for (int k = 0; k < V; ++k) {
        ru[k] = __int_as_float(__float_as_int(ru[k]) ^ m);
        rv[k] = __int_as_float(__float_as_int(rv[k]) ^ m);
    }
}

// ---- min-only cross CE: partner arrives in complementary sign-space ----
template<int CTRL>
__device__ __forceinline__ void minpass_d(float r[V]) {
    #pragma unroll
    for (int k = 0; k < V; ++k) {
        int o = __builtin_amdgcn_mov_dpp(__float_as_int(r[k]), CTRL, 0xF, 0xF, true);
        r[k] = fminf(r[k], __int_as_float(o ^ (int)SGN));
    }
}
__device__ __forceinline__ void minpass_b(float r[V], int pa) {
    #pragma unroll
    for (int k = 0; k < V; ++k) {
        int o = __builtin_amdgcn_ds_bpermute(pa, __float_as_int(r[k]));
        r[k] = fminf(r[k], __int_as_float(o ^ (int)SGN));
    }
}

// ---- cross passes m=2^MMAXLOG..1 (entry space must include pm[MMAXLOG]),
//      per-pass space transitions, then ascending register tail.
//      Exits in stage-sign space. ----
template<int MMAXLOG>
__device__ __forceinline__ void stage_cross(float ru[V], float rv[V],
                                            const unsigned pm[6], int lane) {
    #pragma unroll
    for (int ml = MMAXLOG; ml >= 0; --ml) {
        const int m = 1 << ml;
        if (ml == 0)      { minpass_d<0xB1>(ru); minpass_d<0xB1>(rv); }  // xor1
        else if (ml == 1) { minpass_d<0x4E>(ru); minpass_d<0x4E>(rv); }  // xor2
        else {
            const int pa = (lane ^ m) << 2;
            minpass_b(ru, pa); minpass_b(rv, pa);
        }
        const unsigned tr = (ml > 0) ? (pm[ml] ^ pm[ml - 1]) : pm[0];
        flip2(ru, rv, tr);
    }
    reg_tail_asc(ru);
    reg_tail_asc(rv);
}

__global__ __launch_bounds__(THREADS, 5) void w1_rows_kernel(
    const float* __restrict__ pred,
    const float* __restrict__ tru,
    float* __restrict__ out,
    float scale)
{
    __shared__ float xbuf[THREADS * V];   // exactly 32768 B; swizzled addressing

    const int tid  = threadIdx.x;
    const int t    = tid & 127;           // thread index within the row (0..127)
    const int lane = tid & 63;
    const int row  = blockIdx.x * 2 + (tid >> 7);
    const size_t base = (size_t)row * N_ELEM + (size_t)t * V;

    // Per-lane sign-space masks.
    const unsigned pm[6] = {
        (unsigned)(lane << 31) & SGN,   // pm1
        (unsigned)(lane << 30) & SGN,   // pm2
        (unsigned)(lane << 29) & SGN,   // pm4
        (unsigned)(lane << 28) & SGN,   // pm8
        (unsigned)(lane << 27) & SGN,   // pm16
        (unsigned)(lane << 26) & SGN    // pm32
    };
    const unsigned ss32   = (unsigned)(t << 31) & SGN;
    const unsigned ss64   = (unsigned)(t << 30) & SGN;
    const unsigned ss128  = (unsigned)(t << 29) & SGN;
    const unsigned ss256  = (unsigned)(t << 28) & SGN;
    const unsigned ss512  = (unsigned)(t << 27) & SGN;
    const unsigned ss1024 = (unsigned)(t << 26) & SGN;
    const unsigned ss2048 = (unsigned)(t << 25) & SGN;  // == pm64 (t bit 6)

    // Blocked layout: row-thread t owns global indices [32t, 32t+32).
    float ru[V], rv[V];
    {
        const float4* u4 = (const float4*)(pred + base);
        const float4* v4 = (const float4*)(tru  + base);
        #pragma unroll
        for (int c = 0; c < V / 4; ++c) {
            float4 a = u4[c], b = v4[c];
            ru[4*c+0] = a.x; ru[4*c+1] = a.y; ru[4*c+2] = a.z; ru[4*c+3] = a.w;
            rv[4*c+0] = b.x; rv[4*c+1] = b.y; rv[4*c+2] = b.z; rv[4*c+3] = b.w;
        }
    }

    // Stages S=2..16: in-register, compile-time directions (true space).
    reg_stage_small<2>(ru);  reg_stage_small<2>(rv);
    reg_stage_small<4>(ru);  reg_stage_small<4>(rv);
    reg_stage_small<8>(ru);  reg_stage_small<8>(rv);
    reg_stage_small<16>(ru); reg_stage_small<16>(rv);

    // Stage 32: enter ss32 space, ascending tail.
    flip2(ru, rv, ss32);
    reg_tail_asc(ru); reg_tail_asc(rv);

    // Stages 64..2048: entry flip = prev_ss ^ ss ^ pm[top], then cross+tail.
    flip2(ru, rv, ss32   ^ ss64   ^ pm[0]); stage_cross<0>(ru, rv, pm, lane);
    flip2(ru, rv, ss64   ^ ss128  ^ pm[1]); stage_cross<1>(ru, rv, pm, lane);
    flip2(ru, rv, ss128  ^ ss256  ^ pm[2]); stage_cross<2>(ru, rv, pm, lane);
    flip2(ru, rv, ss256  ^ ss512  ^ pm[3]); stage_cross<3>(ru, rv, pm, lane);
    flip2(ru, rv, ss512  ^ ss1024 ^ pm[4]); stage_cross<4>(ru, rv, pm, lane);
    flip2(ru, rv, ss1024 ^ ss2048 ^ pm[5]); stage_cross<5>(ru, rv, pm, lane);

    // Stage 4096: first pass is thread xor 64 through LDS. Data is already in
    // pm64 space (ss2048 == pm64), so the min-only trick applies directly.
    {
        const int wb = tid << 5;
        const int rb = (tid ^ 64) << 5;

        #pragma unroll
        for (int k = 0; k < V; ++k) xbuf[wb + ((k + tid) & 31)] = ru[k];
        __syncthreads();
        #pragma unroll
        for (int k = 0; k < V; ++k) {
            int o = __float_as_int(xbuf[rb + ((k + tid) & 31)]);
            ru[k] = fminf(ru[k], __int_as_float(o ^ (int)SGN));
        }
        __syncthreads();

        #pragma unroll
        for (int k = 0; k < V; ++k) xbuf[wb + ((k + tid) & 31)] = rv[k];
        __syncthreads();
        #pragma unroll
        for (int k = 0; k < V; ++k) {
            int o = __float_as_int(xbuf[rb + ((k + tid) & 31)]);
            rv[k] = fminf(rv[k], __int_as_float(o ^ (int)SGN));
        }

        // Remaining passes m=32..1 + tail; exits in true space (ss4096 = 0).
        flip2(ru, rv, ss2048 ^ pm[5]);   // pm64 -> pm32 space
        stage_cross<5>(ru, rv, pm, lane);
    }

    // Epilogue: per-thread |diff| sum, wave reduce, block reduce, one atomic.
    float part = 0.f;
    #pragma unroll
    for (int k = 0; k < V; ++k) part += fabsf(ru[k] - rv[k]);

    #pragma unroll
    for (int off = 32; off > 0; off >>= 1)
        part += __shfl_down(part, off, 64);

    __syncthreads();                      // xbuf reads done; safe to reuse
    float* wsum = xbuf;
    const int wid = tid >> 6;
    if (lane == 0) wsum[wid] = part;
    __syncthreads();
    if (tid == 0) {
        float tot = wsum[0] + wsum[1] + wsum[2] + wsum[3];
        atomicAdd(out, tot * scale);
    }
}

extern "C" void kernel_launch(void* const* d_in, const int* in_sizes, int n_in,
                              void* d_out, int out_size, void* d_ws, size_t ws_size,
                              hipStream_t stream)
{
    (void)n_in; (void)out_size; (void)d_ws; (void)ws_size;

    const float* pred = (const float*)d_in[0];
    const float* tru  = (const float*)d_in[1];
    float* out = (float*)d_out;

    const int B = in_sizes[0] / N_ELEM;   // 4096 rows

    hipMemsetAsync(out, 0, sizeof(float), stream);

    const float scale = 1.0f / ((float)N_ELEM * (float)B);
    w1_rows_kernel<<<B / 2, THREADS, 0, stream>>>(pred, tru, out, scale);
}

// Round 6
// 296.308 us; speedup vs baseline: 1.0791x; 1.0791x over previous
//
#include <hip/hip_runtime.h>

// WassersteinLoss: per-row W1 = (1/N) * sum_i |sort(u)[i] - sort(v)[i]|, mean over rows.
// R6: V=32, 2 waves/row, negated-partner min-only bitonic (R5 machinery, verified
//   absmax 0) -- but u and v sorted SEQUENTIALLY: only 32 data regs live during a
//   sort, sorted-u parks in registers untouched during v's sort. Peak demand ~80
//   regs < 128 budget at (256,4): no AGPR shuffle moves, no scratch.
// R5 post-mortem: (256,5) squeezed budget to ~96 -> scratch spill (WRITE_SIZE 161 MB).
// R4 post-mortem: interleaved u+v (64 live floats) -> AGPR shuffling ~= 16K extra
//   VALU instr/thread (measured 26K vs 10K static).

constexpr int N_ELEM  = 4096;
constexpr int V       = 32;     // elements per thread per array
constexpr int THREADS = 256;    // 4 waves = 2 rows per block
constexpr unsigned SGN = 0x80000000u;

// ---- compile-time small stages S=2..16 (directions depend on k only) ----
template<int S>
__device__ __forceinline__ void reg_stage_small(float r[V]) {
    #pragma unroll
    for (int s = S >> 1; s >= 1; s >>= 1) {
        #pragma unroll
        for (int k = 0; k < V; ++k) {
            if ((k & s) == 0) {
                const bool asc = ((k & S) == 0);
                float a = r[k], b = r[k + s];
                float lo = fminf(a, b), hi = fmaxf(a, b);
                r[k]     = asc ? lo : hi;
                r[k + s] = asc ? hi : lo;
            }
        }
    }
}

// ---- ascending-only register merge tail, strides 16..1 (2 ops/CE) ----
__device__ __forceinline__ void reg_tail_asc(float r[V]) {
    #pragma unroll
    for (int s = 16; s >= 1; s >>= 1) {
        #pragma unroll
        for (int k = 0; k < V; ++k) {
            if ((k & s) == 0) {
                float a = r[k], b = r[k + s];
                r[k]     = fminf(a, b);
                r[k + s] = fmaxf(a, b);
            }
        }
    }
}

__device__ __forceinline__ void flip1(float r[V], unsigned m) {
    #pragma unroll
    for (int k = 0; k < V; ++k)
        r[k] = __int_as_float(__float_as_int(r[k]) ^ m);
}

// ---- min-only cross CE: partner arrives in complementary sign-space ----
template<int CTRL>
__device__ __forceinline__ void minpass_d(float r[V]) {
    #pragma unroll
    for (int k = 0; k < V; ++k) {
        int o = __builtin_amdgcn_mov_dpp(__float_as_int(r[k]), CTRL, 0xF, 0xF, true);
        r[k] = fminf(r[k], __int_as_float(o ^ (int)SGN));
    }
}
__device__ __forceinline__ void minpass_b(float r[V], int pa) {
    #pragma unroll
    for (int k = 0; k < V; ++k) {
        int o = __builtin_amdgcn_ds_bpermute(pa, __float_as_int(r[k]));
        r[k] = fminf(r[k], __int_as_float(o ^ (int)SGN));
    }
}

// ---- cross passes m=2^MMAXLOG..1 (entry space must include pm[MMAXLOG]),
//      per-pass space transitions, then ascending register tail.
//      Exits in stage-sign space. ----
template<int MMAXLOG>
__device__ __forceinline__ void stage_cross(float r[V], const unsigned pm[6], int lane) {
    #pragma unroll
    for (int ml = MMAXLOG; ml >= 0; --ml) {
        if (ml == 0)      minpass_d<0xB1>(r);                       // lane xor 1
        else if (ml == 1) minpass_d<0x4E>(r);                       // lane xor 2
        else              minpass_b(r, (lane ^ (1 << ml)) << 2);    // lane xor 4..32
        flip1(r, (ml > 0) ? (pm[ml] ^ pm[ml - 1]) : pm[0]);
    }
    reg_tail_asc(r);
}

struct SortCtx {
    unsigned pm[6];   // per-lane pass masks (m = 1..32)
    unsigned ss[7];   // stage sign masks (S = 32..2048)
    int t, lane, tid;
};

// ---- full bitonic sort of one 4096-row chunk (V elems/thread, 128 threads/row) ----
__device__ __forceinline__ void sort_row(float r[V], const SortCtx& c, float* xbuf) {
    // Stages 2..16: in-register, true space.
    reg_stage_small<2>(r);  reg_stage_small<4>(r);
    reg_stage_small<8>(r);  reg_stage_small<16>(r);

    // Stage 32: enter ss32 space, ascending tail.
    flip1(r, c.ss[0]);
    reg_tail_asc(r);

    // Stages 64..2048.
    flip1(r, c.ss[0] ^ c.ss[1] ^ c.pm[0]); stage_cross<0>(r, c.pm, c.lane);
    flip1(r, c.ss[1] ^ c.ss[2] ^ c.pm[1]); stage_cross<1>(r, c.pm, c.lane);
    flip1(r, c.ss[2] ^ c.ss[3] ^ c.pm[2]); stage_cross<2>(r, c.pm, c.lane);
    flip1(r, c.ss[3] ^ c.ss[4] ^ c.pm[3]); stage_cross<3>(r, c.pm, c.lane);
    flip1(r, c.ss[4] ^ c.ss[5] ^ c.pm[4]); stage_cross<4>(r, c.pm, c.lane);
    flip1(r, c.ss[5] ^ c.ss[6] ^ c.pm[5]); stage_cross<5>(r, c.pm, c.lane);

    // Stage 4096: thread-xor-64 pass through LDS. Data already sits in pm64
    // space (ss2048 == pm64), so the min-only trick applies directly.
    {
        const int wb = c.tid << 5;
        const int rb = (c.tid ^ 64) << 5;
        #pragma unroll
        for (int k = 0; k < V; ++k) xbuf[wb + ((k + c.tid) & 31)] = r[k];
        __syncthreads();
        #pragma unroll
        for (int k = 0; k < V; ++k) {
            int o = __float_as_int(xbuf[rb + ((k + c.tid) & 31)]);
            r[k] = fminf(r[k], __int_as_float(o ^ (int)SGN));
        }
        __syncthreads();   // xbuf free for the next user
    }
    // Remaining passes m=32..1 + tail; exits in true space (stage sign = 0).
    flip1(r, c.ss[6] ^ c.pm[5]);
    stage_cross<5>(r, c.pm, c.lane);
}

__global__ __launch_bounds__(THREADS, 4) void w1_rows_kernel(
    const float* __restrict__ pred,
    const float* __restrict__ tru,
    float* __restrict__ out,
    float scale)
{
    __shared__ float xbuf[THREADS * V];   // 32 KB: exchange buffer + final reduce

    SortCtx c;
    c.tid  = threadIdx.x;
    c.t    = c.tid & 127;                 // thread index within the row
    c.lane = c.tid & 63;
    #pragma unroll
    for (int i = 0; i < 6; ++i)
        c.pm[i] = (unsigned)(c.lane << (31 - i)) & SGN;
    #pragma unroll
    for (int i = 0; i < 7; ++i)
        c.ss[i] = (unsigned)(c.t << (31 - i)) & SGN;  // ss[6] == pm64 (t bit 6)

    const int row = blockIdx.x * 2 + (c.tid >> 7);
    const size_t base = (size_t)row * N_ELEM + (size_t)c.t * V;

    // ---- sort u ----
    float ru[V];
    {
        const float4* u4 = (const float4*)(pred + base);
        #pragma unroll
        for (int q = 0; q < V / 4; ++q) {
            float4 a = u4[q];
            ru[4*q+0] = a.x; ru[4*q+1] = a.y; ru[4*q+2] = a.z; ru[4*q+3] = a.w;
        }
    }
    sort_row(ru, c, xbuf);

    // ---- sort v (ru parks untouched in registers) ----
    float rv[V];
    {
        const float4* v4 = (const float4*)(tru + base);
        #pragma unroll
        for (int q = 0; q < V / 4; ++q) {
            float4 a = v4[q];
            rv[4*q+0] = a.x; rv[4*q+1] = a.y; rv[4*q+2] = a.z; rv[4*q+3] = a.w;
        }
    }
    sort_row(rv, c, xbuf);

    // ---- epilogue: |diff| sum, wave reduce, block reduce, one atomic ----
    float part = 0.f;
    #pragma unroll
    for (int k = 0; k < V; ++k) part += fabsf(ru[k] - rv[k]);

    #pragma unroll
    for (int off = 32; off > 0; off >>= 1)
        part += __shfl_down(part, off, 64);

    float* wsum = xbuf;                   // safe: barrier at end of sort_row
    const int wid = c.tid >> 6;
    if (c.lane == 0) wsum[wid] = part;
    __syncthreads();
    if (c.tid == 0) {
        float tot = wsum[0] + wsum[1] + wsum[2] + wsum[3];
        atomicAdd(out, tot * scale);
    }
}

extern "C" void kernel_launch(void* const* d_in, const int* in_sizes, int n_in,
                              void* d_out, int out_size, void* d_ws, size_t ws_size,
                              hipStream_t stream)
{
    (void)n_in; (void)out_size; (void)d_ws; (void)ws_size;

    const float* pred = (const float*)d_in[0];
    const float* tru  = (const float*)d_in[1];
    float* out = (float*)d_out;

    const int B = in_sizes[0] / N_ELEM;   // 4096 rows

    hipMemsetAsync(out, 0, sizeof(float), stream);

    const float scale = 1.0f / ((float)N_ELEM * (float)B);
    w1_rows_kernel<<<B / 2, THREADS, 0, stream>>>(pred, tru, out, scale);
}

// Round 7
// 292.142 us; speedup vs baseline: 1.0945x; 1.0143x over previous
//
#include <hip/hip_runtime.h>

// WassersteinLoss: per-row W1 = (1/N) * sum_i |sort(u)[i] - sort(v)[i]|, mean over rows.
// R7: V=16, 256 threads/row (1 row/block, grid 4096). Everything sized to fit
//   ~60 arch VGPRs: 16 data + 16 parked sorted-u + temps. No AGPR split, no spill.
//   Negated-partner min-only bitonic (validated absmax 0 in R5/R6):
//     cross CE = fminf(r, -perm(r)) -- fneg folds into v_min_f32 src modifier.
//   Cross passes: dpp xor1/2, bpermute xor4..32, LDS t^64/t^128 (stride-17 pad).
//   All sign/pass masks are single t-bits: sb[j] = ((t>>j)&1)<<31.
// R4-R6 post-mortem: >64-float working sets pay the unified-RF tax (64 arch
//   VGPR + AGPR shuffle + scratch spill: R6 WRITE_SIZE 53 MB, ~3x VALU inflation).

constexpr int N_ELEM  = 4096;
constexpr int V       = 16;     // elements per thread per array
constexpr int THREADS = 256;    // 4 waves = 1 row per block
constexpr unsigned SGN = 0x80000000u;

// ---- compile-time small stages S=2..8 (directions depend on k only) ----
template<int S>
__device__ __forceinline__ void reg_stage_small(float r[V]) {
    #pragma unroll
    for (int s = S >> 1; s >= 1; s >>= 1) {
        #pragma unroll
        for (int k = 0; k < V; ++k) {
            if ((k & s) == 0) {
                const bool asc = ((k & S) == 0);
                float a = r[k], b = r[k + s];
                float lo = fminf(a, b), hi = fmaxf(a, b);
                r[k]     = asc ? lo : hi;
                r[k + s] = asc ? hi : lo;
            }
        }
    }
}

// ---- ascending-only register merge tail, strides 8..1 (2 ops/CE) ----
__device__ __forceinline__ void reg_tail_asc(float r[V]) {
    #pragma unroll
    for (int s = 8; s >= 1; s >>= 1) {
        #pragma unroll
        for (int k = 0; k < V; ++k) {
            if ((k & s) == 0) {
                float a = r[k], b = r[k + s];
                r[k]     = fminf(a, b);
                r[k + s] = fmaxf(a, b);
            }
        }
    }
}

__device__ __forceinline__ void flip1(float r[V], unsigned m) {
    #pragma unroll
    for (int k = 0; k < V; ++k)
        r[k] = __int_as_float(__float_as_int(r[k]) ^ m);
}

// ---- min-only cross CEs: partner arrives in complementary sign-space ----
template<int CTRL>
__device__ __forceinline__ void minpass_dpp(float r[V]) {
    #pragma unroll
    for (int k = 0; k < V; ++k) {
        int o = __builtin_amdgcn_mov_dpp(__float_as_int(r[k]), CTRL, 0xF, 0xF, true);
        r[k] = fminf(r[k], -__int_as_float(o));   // fneg folds into v_min_f32
    }
}
__device__ __forceinline__ void minpass_bp(float r[V], int pa) {
    #pragma unroll
    for (int k = 0; k < V; ++k) {
        int o = __builtin_amdgcn_ds_bpermute(pa, __float_as_int(r[k]));
        r[k] = fminf(r[k], -__int_as_float(o));
    }
}
// thread xor 64 / 128 through LDS; stride 17 (odd) -> 2-way bank alias = free
__device__ __forceinline__ void minpass_lds(float r[V], float* xbuf, int tid, int xm) {
    const int wb = tid * 17;
    const int rb = (tid ^ xm) * 17;
    #pragma unroll
    for (int k = 0; k < V; ++k) xbuf[wb + k] = r[k];
    __syncthreads();
    #pragma unroll
    for (int k = 0; k < V; ++k)
        r[k] = fminf(r[k], -xbuf[rb + k]);
    __syncthreads();
}

// ---- stage I (S = 2^(4+I), I=1..8): entry flip = ss_I, cross passes j=I-1..0,
//      per-pass space transitions, ascending tail. Exits in ss_I space. ----
template<int I>
__device__ __forceinline__ void stage(float r[V], const unsigned sb[8],
                                      int lane, int tid, float* xbuf) {
    if constexpr (I < 8) flip1(r, sb[I]);   // stage 4096: ss = 0, free entry
    #pragma unroll
    for (int j = I - 1; j >= 0; --j) {
        if (j == 0)      minpass_dpp<0xB1>(r);                     // t xor 1
        else if (j == 1) minpass_dpp<0x4E>(r);                     // t xor 2
        else if (j <= 5) minpass_bp(r, (lane ^ (1 << j)) << 2);    // t xor 4..32
        else             minpass_lds(r, xbuf, tid, 1 << j);        // t xor 64/128
        flip1(r, (j > 0) ? (sb[j] ^ sb[j - 1]) : sb[0]);
    }
    reg_tail_asc(r);
}

// ---- full bitonic sort of one 4096 row (16 elems/thread, 256 threads) ----
__device__ __forceinline__ void sort_row(float r[V], const unsigned sb[8],
                                         int lane, int tid, float* xbuf) {
    reg_stage_small<2>(r);
    reg_stage_small<4>(r);
    reg_stage_small<8>(r);
    flip1(r, sb[0]);         // stage 16: enter ss space, ascending tail
    reg_tail_asc(r);
    stage<1>(r, sb, lane, tid, xbuf);   // S=32
    stage<2>(r, sb, lane, tid, xbuf);   // S=64
    stage<3>(r, sb, lane, tid, xbuf);   // S=128
    stage<4>(r, sb, lane, tid, xbuf);   // S=256
    stage<5>(r, sb, lane, tid, xbuf);   // S=512
    stage<6>(r, sb, lane, tid, xbuf);   // S=1024
    stage<7>(r, sb, lane, tid, xbuf);   // S=2048 (1 LDS pass)
    stage<8>(r, sb, lane, tid, xbuf);   // S=4096 (2 LDS passes) -> true space
}

__global__ __launch_bounds__(THREADS, 6) void w1_rows_kernel(
    const float* __restrict__ pred,
    const float* __restrict__ tru,
    float* __restrict__ out,
    float scale)
{
    __shared__ float xbuf[THREADS * 17];   // 17408 B exchange buffer (+ reduce)

    const int tid  = threadIdx.x;
    const int lane = tid & 63;

    unsigned sb[8];
    #pragma unroll
    for (int j = 0; j < 8; ++j)
        sb[j] = (unsigned)(tid << (31 - j)) & SGN;   // t-bit j as sign mask

    const size_t base = (size_t)blockIdx.x * N_ELEM + (size_t)tid * V;

    // ---- sort u ----
    float ru[V];
    {
        const float4* u4 = (const float4*)(pred + base);
        #pragma unroll
        for (int q = 0; q < V / 4; ++q) {
            float4 a = u4[q];
            ru[4*q+0] = a.x; ru[4*q+1] = a.y; ru[4*q+2] = a.z; ru[4*q+3] = a.w;
        }
    }
    sort_row(ru, sb, lane, tid, xbuf);

    // ---- sort v (sorted u parks in 16 registers, untouched) ----
    float rv[V];
    {
        const float4* v4 = (const float4*)(tru + base);
        #pragma unroll
        for (int q = 0; q < V / 4; ++q) {
            float4 a = v4[q];
            rv[4*q+0] = a.x; rv[4*q+1] = a.y; rv[4*q+2] = a.z; rv[4*q+3] = a.w;
        }
    }
    sort_row(rv, sb, lane, tid, xbuf);

    // ---- epilogue: |diff| sum, wave reduce, block reduce, one atomic ----
    float part = 0.f;
    #pragma unroll
    for (int k = 0; k < V; ++k) part += fabsf(ru[k] - rv[k]);

    #pragma unroll
    for (int off = 32; off > 0; off >>= 1)
        part += __shfl_down(part, off, 64);

    if (lane == 0) xbuf[tid >> 6] = part;   // safe: sort_row's last op barriers
    __syncthreads();
    if (tid == 0) {
        float tot = xbuf[0] + xbuf[1] + xbuf[2] + xbuf[3];
        atomicAdd(out, tot * scale);
    }
}

extern "C" void kernel_launch(void* const* d_in, const int* in_sizes, int n_in,
                              void* d_out, int out_size, void* d_ws, size_t ws_size,
                              hipStream_t stream)
{
    (void)n_in; (void)out_size; (void)d_ws; (void)ws_size;

    const float* pred = (const float*)d_in[0];
    const float* tru  = (const float*)d_in[1];
    float* out = (float*)d_out;

    const int B = in_sizes[0] / N_ELEM;   // 4096 rows

    hipMemsetAsync(out, 0, sizeof(float), stream);

    const float scale = 1.0f / ((float)N_ELEM * (float)B);
    w1_rows_kernel<<<B, THREADS, 0, stream>>>(pred, tru, out, scale);
}

// Round 8
// 291.774 us; speedup vs baseline: 1.0959x; 1.0013x over previous
//
#include <hip/hip_runtime.h>

// WassersteinLoss: per-row W1 = (1/N) * sum_i |sort(u)[i] - sort(v)[i]|, mean over rows.
// R8: identical to R7 except __launch_bounds__(256,4) (was 256,6).
// R7 post-mortem: (256,6) squeezed arch VGPRs to 32 (< the ~56-reg working set)
//   -> compiler parked live values in AGPRs -> v_accvgpr move tax on the VALU
//   pipe (~3x instr inflation: static 4.6K vs implied 15K instr/thread).
//   (256,4) caps at 128: honest ~60-reg allocation, no churn. Single-variable
//   experiment; VGPR_Count is the diagnostic.

constexpr int N_ELEM  = 4096;
constexpr int V       = 16;     // elements per thread per array
constexpr int THREADS = 256;    // 4 waves = 1 row per block
constexpr unsigned SGN = 0x80000000u;

// ---- compile-time small stages S=2..8 (directions depend on k only) ----
template<int S>
__device__ __forceinline__ void reg_stage_small(float r[V]) {
    #pragma unroll
    for (int s = S >> 1; s >= 1; s >>= 1) {
        #pragma unroll
        for (int k = 0; k < V; ++k) {
            if ((k & s) == 0) {
                const bool asc = ((k & S) == 0);
                float a = r[k], b = r[k + s];
                float lo = fminf(a, b), hi = fmaxf(a, b);
                r[k]     = asc ? lo : hi;
                r[k + s] = asc ? hi : lo;
            }
        }
    }
}

// ---- ascending-only register merge tail, strides 8..1 (2 ops/CE) ----
__device__ __forceinline__ void reg_tail_asc(float r[V]) {
    #pragma unroll
    for (int s = 8; s >= 1; s >>= 1) {
        #pragma unroll
        for (int k = 0; k < V; ++k) {
            if ((k & s) == 0) {
                float a = r[k], b = r[k + s];
                r[k]     = fminf(a, b);
                r[k + s] = fmaxf(a, b);
            }
        }
    }
}

__device__ __forceinline__ void flip1(float r[V], unsigned m) {
    #pragma unroll
    for (int k = 0; k < V; ++k)
        r[k] = __int_as_float(__float_as_int(r[k]) ^ m);
}

// ---- min-only cross CEs: partner arrives in complementary sign-space ----
template<int CTRL>
__device__ __forceinline__ void minpass_dpp(float r[V]) {
    #pragma unroll
    for (int k = 0; k < V; ++k) {
        int o = __builtin_amdgcn_mov_dpp(__float_as_int(r[k]), CTRL, 0xF, 0xF, true);
        r[k] = fminf(r[k], -__int_as_float(o));   // fneg folds into v_min_f32
    }
}
__device__ __forceinline__ void minpass_bp(float r[V], int pa) {
    #pragma unroll
    for (int k = 0; k < V; ++k) {
        int o = __builtin_amdgcn_ds_bpermute(pa, __float_as_int(r[k]));
        r[k] = fminf(r[k], -__int_as_float(o));
    }
}
// thread xor 64 / 128 through LDS; stride 17 (odd) -> 2-way bank alias = free
__device__ __forceinline__ void minpass_lds(float r[V], float* xbuf, int tid, int xm) {
    const int wb = tid * 17;
    const int rb = (tid ^ xm) * 17;
    #pragma unroll
    for (int k = 0; k < V; ++k) xbuf[wb + k] = r[k];
    __syncthreads();
    #pragma unroll
    for (int k = 0; k < V; ++k)
        r[k] = fminf(r[k], -xbuf[rb + k]);
    __syncthreads();
}

// ---- stage I (S = 2^(4+I), I=1..8): entry flip = ss_I, cross passes j=I-1..0,
//      per-pass space transitions, ascending tail. Exits in ss_I space. ----
template<int I>
__device__ __forceinline__ void stage(float r[V], const unsigned sb[8],
                                      int lane, int tid, float* xbuf) {
    if constexpr (I < 8) flip1(r, sb[I]);   // stage 4096: ss = 0, free entry
    #pragma unroll
    for (int j = I - 1; j >= 0; --j) {
        if (j == 0)      minpass_dpp<0xB1>(r);                     // t xor 1
        else if (j == 1) minpass_dpp<0x4E>(r);                     // t xor 2
        else if (j <= 5) minpass_bp(r, (lane ^ (1 << j)) << 2);    // t xor 4..32
        else             minpass_lds(r, xbuf, tid, 1 << j);        // t xor 64/128
        flip1(r, (j > 0) ? (sb[j] ^ sb[j - 1]) : sb[0]);
    }
    reg_tail_asc(r);
}

// ---- full bitonic sort of one 4096 row (16 elems/thread, 256 threads) ----
__device__ __forceinline__ void sort_row(float r[V], const unsigned sb[8],
                                         int lane, int tid, float* xbuf) {
    reg_stage_small<2>(r);
    reg_stage_small<4>(r);
    reg_stage_small<8>(r);
    flip1(r, sb[0]);         // stage 16: enter ss space, ascending tail
    reg_tail_asc(r);
    stage<1>(r, sb, lane, tid, xbuf);   // S=32
    stage<2>(r, sb, lane, tid, xbuf);   // S=64
    stage<3>(r, sb, lane, tid, xbuf);   // S=128
    stage<4>(r, sb, lane, tid, xbuf);   // S=256
    stage<5>(r, sb, lane, tid, xbuf);   // S=512
    stage<6>(r, sb, lane, tid, xbuf);   // S=1024
    stage<7>(r, sb, lane, tid, xbuf);   // S=2048 (1 LDS pass)
    stage<8>(r, sb, lane, tid, xbuf);   // S=4096 (2 LDS passes) -> true space
}

__global__ __launch_bounds__(THREADS, 4) void w1_rows_kernel(
    const float* __restrict__ pred,
    const float* __restrict__ tru,
    float* __restrict__ out,
    float scale)
{
    __shared__ float xbuf[THREADS * 17];   // 17408 B exchange buffer (+ reduce)

    const int tid  = threadIdx.x;
    const int lane = tid & 63;

    unsigned sb[8];
    #pragma unroll
    for (int j = 0; j < 8; ++j)
        sb[j] = (unsigned)(tid << (31 - j)) & SGN;   // t-bit j as sign mask

    const size_t base = (size_t)blockIdx.x * N_ELEM + (size_t)tid * V;

    // ---- sort u ----
    float ru[V];
    {
        const float4* u4 = (const float4*)(pred + base);
        #pragma unroll
        for (int q = 0; q < V / 4; ++q) {
            float4 a = u4[q];
            ru[4*q+0] = a.x; ru[4*q+1] = a.y; ru[4*q+2] = a.z; ru[4*q+3] = a.w;
        }
    }
    sort_row(ru, sb, lane, tid, xbuf);

    // ---- sort v (sorted u parks in 16 registers, untouched) ----
    float rv[V];
    {
        const float4* v4 = (const float4*)(tru + base);
        #pragma unroll
        for (int q = 0; q < V / 4; ++q) {
            float4 a = v4[q];
            rv[4*q+0] = a.x; rv[4*q+1] = a.y; rv[4*q+2] = a.z; rv[4*q+3] = a.w;
        }
    }
    sort_row(rv, sb, lane, tid, xbuf);

    // ---- epilogue: |diff| sum, wave reduce, block reduce, one atomic ----
    float part = 0.f;
    #pragma unroll
    for (int k = 0; k < V; ++k) part += fabsf(ru[k] - rv[k]);

    #pragma unroll
    for (int off = 32; off > 0; off >>= 1)
        part += __shfl_down(part, off, 64);

    if (lane == 0) xbuf[tid >> 6] = part;   // safe: sort_row's last op barriers
    __syncthreads();
    if (tid == 0) {
        float tot = xbuf[0] + xbuf[1] + xbuf[2] + xbuf[3];
        atomicAdd(out, tot * scale);
    }
}

extern "C" void kernel_launch(void* const* d_in, const int* in_sizes, int n_in,
                              void* d_out, int out_size, void* d_ws, size_t ws_size,
                              hipStream_t stream)
{
    (void)n_in; (void)out_size; (void)d_ws; (void)ws_size;

    const float* pred = (const float*)d_in[0];
    const float* tru  = (const float*)d_in[1];
    float* out = (float*)d_out;

    const int B = in_sizes[0] / N_ELEM;   // 4096 rows

    hipMemsetAsync(out, 0, sizeof(float), stream);

    const float scale = 1.0f / ((float)N_ELEM * (float)B);
    w1_rows_kernel<<<B, THREADS, 0, stream>>>(pred, tru, out, scale);
}